// Round 4
// baseline (2563.678 us; speedup 1.0000x reference)
//
#include <hip/hip_runtime.h>
#include <hip/hip_fp16.h>
#include <math.h>

// Problem constants
#define N_ROWS 32768
#define K_CODES 8192
#define DIM 512

// Output layout (floats): quantized_st[N,D], probs[N,K], loss, perplexity
#define OUT_Q 0
#define OUT_P ((size_t)N_ROWS * DIM)                       // 16777216
#define OUT_LOSS (OUT_P + (size_t)N_ROWS * K_CODES)        // 285212672
#define OUT_PERP (OUT_LOSS + 1)

// Workspace layout (float offsets).
#define WS_WSQ 0                         // 8192 floats
#define WS_CNT (K_CODES)                 // 8192 floats (histogram)
#define WS_ERR (2 * K_CODES)             // 32768 floats (per-row sq-err)
#define WS_RED (2 * K_CODES + N_ROWS)    // 64 floats (finalize partials)
#define WS_ROWMI (WS_RED + 64)           // 65536 floats: per-row (M, inv) float2
#define WS_PSUM (WS_ROWMI + 2 * N_ROWS)  // 2097152 floats: [32768][64] tile expsum
#define WS_PMIN (WS_PSUM + (size_t)N_ROWS * 64)  // [32768][64] u64 packed min (4194304 floats)
// byte offset of WS_PMIN = 8847616 (8-aligned OK)
#define WS_F16_FULL (WS_PMIN + (size_t)2 * N_ROWS * 64)  // byte 25624832 (16-aligned)
#define WS_F16_LEG  (WS_RED + 64)        // legacy layout: f16 right after RED (byte 196864)

#define XH_OFF ((size_t)0)
#define XL_OFF ((size_t)N_ROWS * DIM)
#define WH_OFF ((size_t)2 * N_ROWS * DIM)
#define WL_OFF ((size_t)2 * N_ROWS * DIM + (size_t)K_CODES * DIM)
#define F16_COUNT ((size_t)2 * (N_ROWS + K_CODES) * DIM)   // 41943040 halves
#define NEEDED_FULL ((size_t)WS_F16_FULL * 4 + F16_COUNT * 2)   // ~109.5 MB
#define NEEDED_LEG  ((size_t)WS_F16_LEG * 4 + F16_COUNT * 2)    // ~84.1 MB

typedef _Float16 f16x8 __attribute__((ext_vector_type(8)));
typedef float f32x4 __attribute__((ext_vector_type(4)));
typedef unsigned long long u64;

__device__ inline void load_lds16(const void* g, void* l) {
    __builtin_amdgcn_global_load_lds((const __attribute__((address_space(1))) void*)g,
                                     (__attribute__((address_space(3))) void*)l,
                                     16, 0, 0);
}

// Monotone float->uint key: uint order == float order (handles negatives).
__device__ inline unsigned int fkey(float f) {
    unsigned int b = __float_as_uint(f);
    return b ^ ((unsigned int)((int)b >> 31) | 0x80000000u);
}
__device__ inline float fkey_inv(unsigned int k) {
    unsigned int b = (k & 0x80000000u) ? (k ^ 0x80000000u) : ~k;
    return __uint_as_float(b);
}

// ---------------------------------------------------------------------------
// Kernel 0 (fp32 fallback path only): row squared norms for W.
// ---------------------------------------------------------------------------
__global__ void wsq_kernel(const float* __restrict__ W, float* __restrict__ ws) {
    int row = blockIdx.x;
    int lane = threadIdx.x;  // 0..63
    const float* src = W + (size_t)row * DIM;
    float4 v0 = *(const float4*)(src + lane * 8);
    float4 v1 = *(const float4*)(src + lane * 8 + 4);
    float s = v0.x * v0.x + v0.y * v0.y + v0.z * v0.z + v0.w * v0.w
            + v1.x * v1.x + v1.y * v1.y + v1.z * v1.z + v1.w * v1.w;
#pragma unroll
    for (int off = 32; off > 0; off >>= 1) s += __shfl_down(s, off, 64);
    if (lane == 0) ws[WS_WSQ + row] = s;
}

// ---------------------------------------------------------------------------
// Kernel 0b: split X and W into fp16 hi/lo pairs + fused W row norms.
// ---------------------------------------------------------------------------
__global__ void __launch_bounds__(256) convert_split_kernel(
    const float* __restrict__ X, const float* __restrict__ W,
    _Float16* __restrict__ f16base, float* __restrict__ ws) {
    const size_t NX8 = (size_t)N_ROWS * DIM / 8;  // 2097152
    size_t t = (size_t)blockIdx.x * 256 + threadIdx.x;
    const float* src;
    _Float16 *hd, *ld;
    bool isW = (t >= NX8);
    if (!isW) {
        src = X + t * 8;
        hd = f16base + XH_OFF + t * 8;
        ld = f16base + XL_OFF + t * 8;
    } else {
        size_t u = t - NX8;
        src = W + u * 8;
        hd = f16base + WH_OFF + u * 8;
        ld = f16base + WL_OFF + u * 8;
    }
    float4 v0 = *(const float4*)src;
    float4 v1 = *(const float4*)(src + 4);
    float v[8] = {v0.x, v0.y, v0.z, v0.w, v1.x, v1.y, v1.z, v1.w};
    f16x8 h, l;
    float s = 0.f;
#pragma unroll
    for (int i = 0; i < 8; ++i) {
        _Float16 hv = (_Float16)v[i];
        h[i] = hv;
        l[i] = (_Float16)(v[i] - (float)hv);
        s += v[i] * v[i];
    }
    *(f16x8*)hd = h;
    *(f16x8*)ld = l;
    if (isW) {  // wave-uniform branch (W region is wave-aligned)
#pragma unroll
        for (int off = 32; off > 0; off >>= 1) s += __shfl_down(s, off, 64);
        if ((threadIdx.x & 63) == 0) ws[WS_WSQ + ((t - NX8) >> 6)] = s;
    }
}

// ---------------------------------------------------------------------------
// Kernel 1 (MFMA): S[m,n] = wsq[n] - 2 * (x_m . w_n) via fp16 3-term split.
// K-loop: round-1 2-phase schedule restored verbatim (measured best: 903 vs
// 966 1-barrier vs 1002 4-phase). Stripe XCD swizzle kept (FETCH halved).
// NEW: epilogue also emits per-(row, bn-tile) softmax partials:
//   pmin[row][tile] = packed u64 (fkey(min S) << 32 | argcol)
//   psum[row][tile] = sum_cols exp(min_tile - S)
// so the downstream softmax pass becomes a pure stream (no row reductions).
// ---------------------------------------------------------------------------
#define LDSB 24576   // halves per buffer (Ah 8192 | Al 8192 | Bh 4096 | Bl 4096)
#define AH_O 0
#define AL_O 8192
#define BH_O 16384
#define BL_O 20480

__global__ void __launch_bounds__(512, 2) gemm_dist_mfma_kernel(
    const _Float16* __restrict__ f16base, const float* __restrict__ ws,
    float* __restrict__ out, u64* __restrict__ pmin_g,
    float* __restrict__ psum_g) {
    __shared__ __align__(16) _Float16 lds[3 * LDSB];  // 144 KiB

    const int tid = threadIdx.x;
    const int w = tid >> 6;     // wave 0..7
    const int lane = tid & 63;

    // XCD-aware 2D swizzle (bijective): xcd owns an 8-tile bn stripe
    // (W slice 2.1 MB, L2-resident); bm advances every 8 blocks.
    int lin = blockIdx.y * 64 + blockIdx.x;
    int xcd = lin & 7;
    int idx = lin >> 3;
    const int bn = (xcd * 8 + (idx & 7)) * 128;   // 64 bn tiles
    const int bm = (idx >> 3) * 256;              // 128 bm tiles
    const int tile = bn >> 7;                     // 0..63

    const int wr = w >> 1;      // m-quadrant 0..3 (64 rows each)
    const int wc = w & 1;       // n-half     0..1 (64 cols each)
    const int q = lane >> 4;    // frag k-chunk 0..3
    const int fm = lane & 15;   // frag row/col within 16
    const int l4 = lane >> 2;   // stage: row within 16-row group
    const int p = lane & 3;     // stage: chunk position

    f32x4 acc[4][4];
#pragma unroll
    for (int i = 0; i < 4; ++i)
#pragma unroll
        for (int j = 0; j < 4; ++j) acc[i][j] = (f32x4){0.f, 0.f, 0.f, 0.f};

    auto stage = [&](int ks, _Float16* buf, int part) {
        const int kk = ks * 32;
        int g = w * 2 + part;
        int arow = g * 16 + l4;
        int ca = p ^ ((arow >> 1) & 3);
        size_t aoff = (size_t)(bm + arow) * DIM + kk + ca * 8;
        load_lds16(f16base + XH_OFF + aoff, buf + AH_O + g * 512);
        load_lds16(f16base + XL_OFF + aoff, buf + AL_O + g * 512);
        int brow = w * 16 + l4;
        int cb = p ^ ((brow >> 1) & 3);
        size_t boff = (size_t)(bn + brow) * DIM + kk + cb * 8;
        if (part == 0)
            load_lds16(f16base + WH_OFF + boff, buf + BH_O + w * 512);
        else
            load_lds16(f16base + WL_OFF + boff, buf + BL_O + w * 512);
    };

    _Float16* c0 = lds;
    _Float16* c1 = lds + LDSB;
    _Float16* c2 = lds + 2 * LDSB;

    // Prologue: stage ks0 -> c0 (6 loads), ks1 -> c1 (6 loads); wait for c0.
    stage(0, c0, 0); stage(0, c0, 1);
    stage(1, c1, 0); stage(1, c1, 1);
    asm volatile("s_waitcnt vmcnt(6)" ::: "memory");
    __builtin_amdgcn_s_barrier();
    __builtin_amdgcn_sched_barrier(0);

#pragma unroll 1
    for (int ks = 0; ks < 16; ++ks) {
        // ---- phase 1: all B frags + A(i=0,1); stage part 0 of ks+2 ----
        f16x8 bhv[4], blv[4];
#pragma unroll
        for (int j = 0; j < 4; ++j) {
            int bb = wc * 64 + j * 16 + fm;
            int off = bb * 32 + ((q ^ ((bb >> 1) & 3)) * 8);
            bhv[j] = *(const f16x8*)&c0[BH_O + off];
            blv[j] = *(const f16x8*)&c0[BL_O + off];
        }
        f16x8 ah[2], al[2];
#pragma unroll
        for (int i = 0; i < 2; ++i) {
            int am = wr * 64 + i * 16 + fm;
            int off = am * 32 + ((q ^ ((am >> 1) & 3)) * 8);
            ah[i] = *(const f16x8*)&c0[AH_O + off];
            al[i] = *(const f16x8*)&c0[AL_O + off];
        }
        if (ks < 14) stage(ks + 2, c2, 0);
        __builtin_amdgcn_s_setprio(1);
#pragma unroll
        for (int i = 0; i < 2; ++i)
#pragma unroll
            for (int j = 0; j < 4; ++j) {
                acc[i][j] = __builtin_amdgcn_mfma_f32_16x16x32_f16(
                    ah[i], bhv[j], acc[i][j], 0, 0, 0);
                acc[i][j] = __builtin_amdgcn_mfma_f32_16x16x32_f16(
                    ah[i], blv[j], acc[i][j], 0, 0, 0);
                acc[i][j] = __builtin_amdgcn_mfma_f32_16x16x32_f16(
                    al[i], bhv[j], acc[i][j], 0, 0, 0);
            }
        __builtin_amdgcn_s_setprio(0);
        __builtin_amdgcn_s_barrier();

        // ---- phase 2: A(i=2,3), reuse B frags; stage part 1 of ks+2 ----
#pragma unroll
        for (int i = 0; i < 2; ++i) {
            int am = wr * 64 + (i + 2) * 16 + fm;
            int off = am * 32 + ((q ^ ((am >> 1) & 3)) * 8);
            ah[i] = *(const f16x8*)&c0[AH_O + off];
            al[i] = *(const f16x8*)&c0[AL_O + off];
        }
        if (ks < 14) stage(ks + 2, c2, 1);
        __builtin_amdgcn_s_setprio(1);
#pragma unroll
        for (int i = 0; i < 2; ++i)
#pragma unroll
            for (int j = 0; j < 4; ++j) {
                acc[i + 2][j] = __builtin_amdgcn_mfma_f32_16x16x32_f16(
                    ah[i], bhv[j], acc[i + 2][j], 0, 0, 0);
                acc[i + 2][j] = __builtin_amdgcn_mfma_f32_16x16x32_f16(
                    ah[i], blv[j], acc[i + 2][j], 0, 0, 0);
                acc[i + 2][j] = __builtin_amdgcn_mfma_f32_16x16x32_f16(
                    al[i], bhv[j], acc[i + 2][j], 0, 0, 0);
            }
        __builtin_amdgcn_s_setprio(0);
        // Retire buffer (ks+1)'s 6 loads; keep (ks+2)'s 6 in flight.
        if (ks < 14) {
            asm volatile("s_waitcnt vmcnt(6)" ::: "memory");
        } else if (ks == 14) {
            asm volatile("s_waitcnt vmcnt(0)" ::: "memory");
        }
        __builtin_amdgcn_s_barrier();
        __builtin_amdgcn_sched_barrier(0);

        _Float16* t0 = c0; c0 = c1; c1 = c2; c2 = t0;
    }

    // Epilogue: S = wsq[n] - 2*dot (store), + softmax tile partials.
    // C/D layout: col = lane&15, row = (lane>>4)*4 + r (m89-verified)
    const float* wsq = ws + WS_WSQ;
    float* Dout = out + OUT_P;
    const int q4 = q * 4;
    float wnj[4];
#pragma unroll
    for (int j = 0; j < 4; ++j) wnj[j] = wsq[bn + wc * 64 + j * 16 + fm];

#pragma unroll
    for (int i = 0; i < 4; ++i) {
#pragma unroll
        for (int j = 0; j < 4; ++j) {
            int n = bn + wc * 64 + j * 16 + fm;
#pragma unroll
            for (int r = 0; r < 4; ++r) {
                int m = bm + wr * 64 + i * 16 + q4 + r;
                Dout[(size_t)m * K_CODES + n] = wnj[j] - 2.f * acc[i][j][r];
            }
        }
    }

    if (pmin_g) {
        // LDS reuse (post final barrier): [256 rows][2 wc] halves
        u64* hmin = (u64*)lds;                 // 4 KB
        float* hsum = (float*)(hmin + 512);    // 2 KB

        // phase A: per-row packed half-min over this wave's 64 cols
#pragma unroll
        for (int i = 0; i < 4; ++i) {
#pragma unroll
            for (int r = 0; r < 4; ++r) {
                u64 bk = ~0ull;
#pragma unroll
                for (int j = 0; j < 4; ++j) {
                    float S = wnj[j] - 2.f * acc[i][j][r];
                    u64 kk = ((u64)fkey(S) << 32) |
                             (unsigned int)(bn + wc * 64 + j * 16 + fm);
                    bk = kk < bk ? kk : bk;
                }
#pragma unroll
                for (int d = 1; d < 16; d <<= 1) {
                    u64 o = __shfl_xor(bk, d, 64);
                    bk = o < bk ? o : bk;
                }
                if (fm == 0) hmin[(wr * 64 + i * 16 + q4 + r) * 2 + wc] = bk;
            }
        }
        __syncthreads();

        // phase B: full-tile min -> exp sums per half
#pragma unroll
        for (int i = 0; i < 4; ++i) {
#pragma unroll
            for (int r = 0; r < 4; ++r) {
                int rl = wr * 64 + i * 16 + q4 + r;
                u64 k0 = hmin[rl * 2 + 0], k1 = hmin[rl * 2 + 1];
                u64 km = k1 < k0 ? k1 : k0;
                float mt = fkey_inv((unsigned int)(km >> 32));
                float s = 0.f;
#pragma unroll
                for (int j = 0; j < 4; ++j)
                    s += __expf(mt - (wnj[j] - 2.f * acc[i][j][r]));
#pragma unroll
                for (int d = 1; d < 16; d <<= 1) s += __shfl_xor(s, d, 64);
                if (fm == 0) hsum[rl * 2 + wc] = s;
            }
        }
        __syncthreads();

        // phase C: wc==0 waves (256 lanes) write per-row tile partials
        if (wc == 0) {
            int rl = wr * 64 + lane;
            u64 k0 = hmin[rl * 2 + 0], k1 = hmin[rl * 2 + 1];
            u64 km = k1 < k0 ? k1 : k0;
            size_t o = (size_t)(bm + rl) * 64 + tile;
            pmin_g[o] = km;
            psum_g[o] = hsum[rl * 2 + 0] + hsum[rl * 2 + 1];
        }
    }
}

// ---------------------------------------------------------------------------
// Kernel C: per-row combine. One wave per row: reduce 64 tile partials ->
// (M, argmin, inv); then quantize (gather W[amin]), write Q, per-row err,
// spread histogram atomic. Writes (M, inv) for the streaming P-pass.
// ---------------------------------------------------------------------------
__global__ void __launch_bounds__(256) combine_kernel(
    const float* __restrict__ X, const float* __restrict__ W,
    float* __restrict__ out, float* __restrict__ ws) {
    const int row = blockIdx.x * 4 + (threadIdx.x >> 6);
    const int lane = threadIdx.x & 63;
    const u64* pmin = (const u64*)(ws + WS_PMIN);
    const float* psum = ws + WS_PSUM;

    u64 k = pmin[(size_t)row * 64 + lane];
    float s = psum[(size_t)row * 64 + lane];

    u64 bk = k;
#pragma unroll
    for (int d = 1; d < 64; d <<= 1) {
        u64 o = __shfl_xor(bk, d, 64);
        bk = o < bk ? o : bk;
    }
    const float M = fkey_inv((unsigned int)(bk >> 32));
    const int amin = (int)(bk & 0xFFFFFFFFu);

    // total = sum_t exp(M - m_t) * s_t   (= sum over all cols exp(M - S))
    float t = __expf(M - fkey_inv((unsigned int)(k >> 32))) * s;
#pragma unroll
    for (int d = 1; d < 64; d <<= 1) t += __shfl_xor(t, d, 64);
    const float inv = 1.0f / t;

    if (lane == 0)
        ((float2*)(ws + WS_ROWMI))[row] = make_float2(M, inv);

    // quantize + err (straight-through output is exactly W[amin])
    const float4* xr = (const float4*)(X + (size_t)row * DIM);
    const float4* wr = (const float4*)(W + (size_t)amin * DIM);
    float4* qr = (float4*)(out + OUT_Q + (size_t)row * DIM);
    float err = 0.f;
#pragma unroll
    for (int t2 = 0; t2 < 2; ++t2) {
        int i = lane + t2 * 64;
        float4 xv = xr[i];
        float4 wv = wr[i];
        qr[i] = wv;
        float dx = wv.x - xv.x, dy = wv.y - xv.y;
        float dz = wv.z - xv.z, dw = wv.w - xv.w;
        err += dx * dx + dy * dy + dz * dz + dw * dw;
    }
#pragma unroll
    for (int d = 1; d < 64; d <<= 1) err += __shfl_xor(err, d, 64);
    if (lane == 0) {
        ws[WS_ERR + row] = err;
        atomicAdd(ws + WS_CNT + amin, 1.0f);  // spread over 8192 addrs
    }
}

// ---------------------------------------------------------------------------
// Kernel P: streaming softmax write. P = exp(M - S) * inv, in place.
// Pure elementwise grid-stride float4 pass (no reductions, no syncs).
// ---------------------------------------------------------------------------
__global__ void __launch_bounds__(256) ppass_kernel(
    float* __restrict__ out, const float* __restrict__ ws) {
    const float2* rowMI = (const float2*)(ws + WS_ROWMI);
    float4* P = (float4*)(out + OUT_P);
    const size_t total4 = (size_t)N_ROWS * K_CODES / 4;  // 67108864
    const size_t stride = (size_t)gridDim.x * 256;
    for (size_t i = (size_t)blockIdx.x * 256 + threadIdx.x; i < total4;
         i += stride) {
        int row = (int)(i >> 11);  // 2048 float4 per row
        float2 mi = rowMI[row];
        float4 v = P[i];
        v.x = __expf(mi.x - v.x) * mi.y;
        v.y = __expf(mi.x - v.y) * mi.y;
        v.z = __expf(mi.x - v.z) * mi.y;
        v.w = __expf(mi.x - v.w) * mi.y;
        P[i] = v;
    }
}

// ---------------------------------------------------------------------------
// Fallback fp32 GEMM (only if ws can't hold f16 buffers): writes S.
// ---------------------------------------------------------------------------
#define BM 128
#define BN 128
#define BK 16

__global__ void __launch_bounds__(256) gemm_dist_fp32_kernel(
    const float* __restrict__ X, const float* __restrict__ W,
    const float* __restrict__ ws, float* __restrict__ out) {
    __shared__ float As[BK][BM];
    __shared__ float Bs[BK][BN];

    const int bn = blockIdx.x * BN;
    const int bm = blockIdx.y * BM;
    const int tid = threadIdx.x;
    const int tx = tid & 15;
    const int ty = tid >> 4;
    const int lr = tid >> 1;
    const int lc = (tid & 1) * 8;

    float acc[8][8];
#pragma unroll
    for (int i = 0; i < 8; ++i)
#pragma unroll
        for (int j = 0; j < 8; ++j) acc[i][j] = 0.f;

    const float* aptr = X + (size_t)(bm + lr) * DIM + lc;
    const float* bptr = W + (size_t)(bn + lr) * DIM + lc;

    for (int k0 = 0; k0 < DIM; k0 += BK) {
        float4 a0 = *(const float4*)(aptr + k0);
        float4 a1 = *(const float4*)(aptr + k0 + 4);
        float4 b0 = *(const float4*)(bptr + k0);
        float4 b1 = *(const float4*)(bptr + k0 + 4);
        __syncthreads();
        As[lc + 0][lr] = a0.x; As[lc + 1][lr] = a0.y;
        As[lc + 2][lr] = a0.z; As[lc + 3][lr] = a0.w;
        As[lc + 4][lr] = a1.x; As[lc + 5][lr] = a1.y;
        As[lc + 6][lr] = a1.z; As[lc + 7][lr] = a1.w;
        Bs[lc + 0][lr] = b0.x; Bs[lc + 1][lr] = b0.y;
        Bs[lc + 2][lr] = b0.z; Bs[lc + 3][lr] = b0.w;
        Bs[lc + 4][lr] = b1.x; Bs[lc + 5][lr] = b1.y;
        Bs[lc + 6][lr] = b1.z; Bs[lc + 7][lr] = b1.w;
        __syncthreads();
#pragma unroll
        for (int kk = 0; kk < BK; ++kk) {
            float a[8], b[8];
            *(float4*)&a[0] = *(const float4*)&As[kk][ty * 8];
            *(float4*)&a[4] = *(const float4*)&As[kk][ty * 8 + 4];
            *(float4*)&b[0] = *(const float4*)&Bs[kk][tx * 8];
            *(float4*)&b[4] = *(const float4*)&Bs[kk][tx * 8 + 4];
#pragma unroll
            for (int i = 0; i < 8; ++i)
#pragma unroll
                for (int j = 0; j < 8; ++j)
                    acc[i][j] = fmaf(a[i], b[j], acc[i][j]);
        }
    }

    const float* wsq = ws + WS_WSQ;
    const int m0 = bm + ty * 8;
    const int n0 = bn + tx * 8;
    float wn[8];
    *(float4*)&wn[0] = *(const float4*)(wsq + n0);
    *(float4*)&wn[4] = *(const float4*)(wsq + n0 + 4);
    float* Dout = out + OUT_P;
#pragma unroll
    for (int i = 0; i < 8; ++i) {
        float4 o0, o1;
        o0.x = wn[0] - 2.f * acc[i][0];
        o0.y = wn[1] - 2.f * acc[i][1];
        o0.z = wn[2] - 2.f * acc[i][2];
        o0.w = wn[3] - 2.f * acc[i][3];
        o1.x = wn[4] - 2.f * acc[i][4];
        o1.y = wn[5] - 2.f * acc[i][5];
        o1.z = wn[6] - 2.f * acc[i][6];
        o1.w = wn[7] - 2.f * acc[i][7];
        float* drow = Dout + (size_t)(m0 + i) * K_CODES + n0;
        *(float4*)(drow) = o0;
        *(float4*)(drow + 4) = o1;
    }
}

// ---------------------------------------------------------------------------
// Legacy kernel 2 (fallback paths): one block (512 thr) per row; full row
// argmin/softmax/quantize fused.
// ---------------------------------------------------------------------------
__global__ void __launch_bounds__(512) probs_quant_kernel(
    const float* __restrict__ X, const float* __restrict__ W,
    float* __restrict__ out, float* __restrict__ ws) {
    const int n = blockIdx.x;
    const int tid = threadIdx.x;
    __shared__ unsigned long long mred[8];
    __shared__ float fred[8];

    float4* Drow4 = (float4*)(out + OUT_P + (size_t)n * K_CODES);
    const float x = X[(size_t)n * DIM + tid];

    float4 e[4];
    unsigned long long best = ~0ull;
#pragma unroll
    for (int t = 0; t < 4; ++t) {
        float4 v = Drow4[tid + t * 512];
        e[t] = v;
        unsigned int c0 = (unsigned int)((tid + t * 512) * 4);
        unsigned long long k;
        k = ((unsigned long long)fkey(v.x) << 32) | (c0 + 0u);
        best = k < best ? k : best;
        k = ((unsigned long long)fkey(v.y) << 32) | (c0 + 1u);
        best = k < best ? k : best;
        k = ((unsigned long long)fkey(v.z) << 32) | (c0 + 2u);
        best = k < best ? k : best;
        k = ((unsigned long long)fkey(v.w) << 32) | (c0 + 3u);
        best = k < best ? k : best;
    }
#pragma unroll
    for (int d = 1; d < 64; d <<= 1) {
        unsigned long long o = __shfl_xor(best, d, 64);
        best = o < best ? o : best;
    }
    if ((tid & 63) == 0) mred[tid >> 6] = best;
    __syncthreads();
    unsigned long long bm = mred[0];
#pragma unroll
    for (int i = 1; i < 8; ++i) bm = mred[i] < bm ? mred[i] : bm;
    const float smin = fkey_inv((unsigned int)(bm >> 32));
    const int amin = (int)(bm & 0xFFFFFFFFu);

    float sum = 0.f;
#pragma unroll
    for (int t = 0; t < 4; ++t) {
        float4 v = e[t];
        float4 ev;
        ev.x = __expf(smin - v.x);
        ev.y = __expf(smin - v.y);
        ev.z = __expf(smin - v.z);
        ev.w = __expf(smin - v.w);
        e[t] = ev;
        sum += ev.x + ev.y + ev.z + ev.w;
    }
#pragma unroll
    for (int off = 32; off > 0; off >>= 1) sum += __shfl_down(sum, off, 64);
    if ((tid & 63) == 0) fred[tid >> 6] = sum;
    __syncthreads();
    float tot = fred[0];
#pragma unroll
    for (int i = 1; i < 8; ++i) tot += fred[i];
    const float inv = 1.0f / tot;

#pragma unroll
    for (int t = 0; t < 4; ++t) {
        float4 ev = e[t];
        ev.x *= inv; ev.y *= inv; ev.z *= inv; ev.w *= inv;
        Drow4[tid + t * 512] = ev;
    }

    const float qv = W[(size_t)amin * DIM + tid];
    out[OUT_Q + (size_t)n * DIM + tid] = qv;
    float d2 = qv - x;
    float err = d2 * d2;
#pragma unroll
    for (int off = 32; off > 0; off >>= 1) err += __shfl_down(err, off, 64);
    __syncthreads();
    if ((tid & 63) == 0) fred[tid >> 6] = err;
    __syncthreads();
    if (tid == 0) {
        float e8 = fred[0];
#pragma unroll
        for (int i = 1; i < 8; ++i) e8 += fred[i];
        ws[WS_ERR + n] = e8;
        atomicAdd(ws + WS_CNT + amin, 1.0f);
    }
}

// ---------------------------------------------------------------------------
// Kernel 3a: 32-block partial reduce of per-row errors + entropy terms.
// ---------------------------------------------------------------------------
__global__ void __launch_bounds__(256) finalize_part_kernel(
    float* __restrict__ ws) {
    __shared__ float red[256];
    const int b = blockIdx.x;   // 0..31
    const int tid = threadIdx.x;

    float errsum = 0.f;
    const int ebase = b * 1024;
#pragma unroll
    for (int j = tid; j < 1024; j += 256) errsum += ws[WS_ERR + ebase + j];

    float p = ws[WS_CNT + b * 256 + tid] * (1.0f / (float)N_ROWS);
    float ent = -p * logf(p + 1e-10f);

    red[tid] = errsum;
    __syncthreads();
    for (int st = 128; st > 0; st >>= 1) {
        if (tid < st) red[tid] += red[tid + st];
        __syncthreads();
    }
    if (tid == 0) ws[WS_RED + b] = red[0];
    __syncthreads();
    red[tid] = ent;
    __syncthreads();
    for (int st = 128; st > 0; st >>= 1) {
        if (tid < st) red[tid] += red[tid + st];
        __syncthreads();
    }
    if (tid == 0) ws[WS_RED + 32 + b] = red[0];
}

// ---------------------------------------------------------------------------
// Kernel 3b: final combine (one wave).
// ---------------------------------------------------------------------------
__global__ void __launch_bounds__(64) finalize_fin_kernel(
    float* __restrict__ out, const float* __restrict__ ws) {
    const int tid = threadIdx.x;
    float ev = tid < 32 ? ws[WS_RED + tid] : 0.f;
    float nv = tid < 32 ? ws[WS_RED + 32 + tid] : 0.f;
#pragma unroll
    for (int off = 32; off > 0; off >>= 1) {
        ev += __shfl_down(ev, off, 64);
        nv += __shfl_down(nv, off, 64);
    }
    if (tid == 0) {
        float mse = ev * (1.0f / ((float)N_ROWS * (float)DIM));
        out[OUT_LOSS] = mse + 0.25f * mse;
        out[OUT_PERP] = expf(nv);
    }
}

// ---------------------------------------------------------------------------
extern "C" void kernel_launch(void* const* d_in, const int* in_sizes, int n_in,
                              void* d_out, int out_size, void* d_ws, size_t ws_size,
                              hipStream_t stream) {
    const float* X = (const float*)d_in[0];  // [32768, 512]
    const float* W = (const float*)d_in[1];  // [8192, 512]
    float* out = (float*)d_out;
    float* ws = (float*)d_ws;

    // zero the histogram (ws is poisoned 0xAA); everything else overwritten
    hipMemsetAsync(ws + WS_CNT, 0, K_CODES * sizeof(float), stream);

    const int conv_blocks =
        (int)(((size_t)(N_ROWS + K_CODES) * DIM / 8 + 255) / 256);

    if (ws_size >= NEEDED_FULL) {
        // Full path: gemm+partials -> combine -> streaming P-pass.
        _Float16* f16base = (_Float16*)(ws + WS_F16_FULL);
        convert_split_kernel<<<conv_blocks, 256, 0, stream>>>(X, W, f16base, ws);

        dim3 ggrid(64, 128);
        gemm_dist_mfma_kernel<<<ggrid, 512, 0, stream>>>(
            f16base, ws, out, (u64*)(ws + WS_PMIN), ws + WS_PSUM);

        combine_kernel<<<N_ROWS / 4, 256, 0, stream>>>(X, W, out, ws);
        ppass_kernel<<<2048, 256, 0, stream>>>(out, ws);
    } else if (ws_size >= NEEDED_LEG) {
        // Legacy path (round-3): fused per-row probs kernel.
        _Float16* f16base = (_Float16*)(ws + WS_F16_LEG);
        convert_split_kernel<<<conv_blocks, 256, 0, stream>>>(X, W, f16base, ws);

        dim3 ggrid(64, 128);
        gemm_dist_mfma_kernel<<<ggrid, 512, 0, stream>>>(
            f16base, ws, out, nullptr, nullptr);

        probs_quant_kernel<<<N_ROWS, 512, 0, stream>>>(X, W, out, ws);
    } else {
        wsq_kernel<<<K_CODES, 64, 0, stream>>>(W, ws);
        dim3 ggrid(K_CODES / BN, N_ROWS / BM);
        gemm_dist_fp32_kernel<<<ggrid, 256, 0, stream>>>(X, W, ws, out);
        probs_quant_kernel<<<N_ROWS, 512, 0, stream>>>(X, W, out, ws);
    }

    finalize_part_kernel<<<32, 256, 0, stream>>>(ws);
    finalize_fin_kernel<<<1, 64, 0, stream>>>(out, ws);
}

// Round 6
// 2261.366 us; speedup vs baseline: 1.1337x; 1.1337x over previous
//
#include <hip/hip_runtime.h>
#include <hip/hip_fp16.h>
#include <math.h>

// Problem constants
#define N_ROWS 32768
#define K_CODES 8192
#define DIM 512

// Output layout (floats): quantized_st[N,D], probs[N,K], loss, perplexity
#define OUT_Q 0
#define OUT_P ((size_t)N_ROWS * DIM)                       // 16777216
#define OUT_LOSS (OUT_P + (size_t)N_ROWS * K_CODES)        // 285212672
#define OUT_PERP (OUT_LOSS + 1)

// Workspace layout (float offsets).
#define WS_WSQ 0                        // 8192 floats
#define WS_CNT (K_CODES)                // 8192 floats (histogram)
#define WS_ERR (2 * K_CODES)            // 32768 floats (per-row sq-err)
#define WS_RED (2 * K_CODES + N_ROWS)   // 64 floats (finalize partials)
#define WS_F16 (WS_RED + 64)            // f16 base (byte 196864, 16-aligned)

// f16 region layout (in _Float16 elements, relative to f16 base)
#define XH_OFF ((size_t)0)
#define XL_OFF ((size_t)N_ROWS * DIM)
#define WH_OFF ((size_t)2 * N_ROWS * DIM)
#define WL_OFF ((size_t)2 * N_ROWS * DIM + (size_t)K_CODES * DIM)
#define F16_COUNT ((size_t)2 * (N_ROWS + K_CODES) * DIM)   // 41943040 halves
#define WS_NEEDED ((size_t)WS_F16 * 4 + F16_COUNT * 2)     // ~84.1 MB

typedef _Float16 f16x8 __attribute__((ext_vector_type(8)));
typedef float f32x4 __attribute__((ext_vector_type(4)));
typedef float f32x2 __attribute__((ext_vector_type(2)));
typedef unsigned long long u64;

__device__ inline void load_lds16(const void* g, void* l) {
    __builtin_amdgcn_global_load_lds((const __attribute__((address_space(1))) void*)g,
                                     (__attribute__((address_space(3))) void*)l,
                                     16, 0, 0);
}

// Non-temporal helpers (streams touched once: keep them out of L2).
__device__ inline f32x4 ntload4(const float* p) {
    return __builtin_nontemporal_load((const f32x4*)p);
}
__device__ inline void ntstore4(float* p, f32x4 v) {
    __builtin_nontemporal_store(v, (f32x4*)p);
}
__device__ inline void ntstore1(float* p, float v) {
    __builtin_nontemporal_store(v, p);
}

// Monotone float->uint key: uint order == float order (handles negatives).
__device__ inline unsigned int fkey(float f) {
    unsigned int b = __float_as_uint(f);
    return b ^ ((unsigned int)((int)b >> 31) | 0x80000000u);
}
__device__ inline float fkey_inv(unsigned int k) {
    unsigned int b = (k & 0x80000000u) ? (k ^ 0x80000000u) : ~k;
    return __uint_as_float(b);
}

// ---------------------------------------------------------------------------
// Kernel 0 (fp32 fallback path only): row squared norms for W.
// ---------------------------------------------------------------------------
__global__ void wsq_kernel(const float* __restrict__ W, float* __restrict__ ws) {
    int row = blockIdx.x;
    int lane = threadIdx.x;  // 0..63
    const float* src = W + (size_t)row * DIM;
    float4 v0 = *(const float4*)(src + lane * 8);
    float4 v1 = *(const float4*)(src + lane * 8 + 4);
    float s = v0.x * v0.x + v0.y * v0.y + v0.z * v0.z + v0.w * v0.w
            + v1.x * v1.x + v1.y * v1.y + v1.z * v1.z + v1.w * v1.w;
#pragma unroll
    for (int off = 32; off > 0; off >>= 1) s += __shfl_down(s, off, 64);
    if (lane == 0) ws[WS_WSQ + row] = s;
}

// ---------------------------------------------------------------------------
// Kernel 0b: split X and W into fp16 hi/lo pairs + fused W row norms.
// f16 outputs are written once, read much later -> non-temporal stores.
// ---------------------------------------------------------------------------
__global__ void __launch_bounds__(256) convert_split_kernel(
    const float* __restrict__ X, const float* __restrict__ W,
    _Float16* __restrict__ f16base, float* __restrict__ ws) {
    const size_t NX8 = (size_t)N_ROWS * DIM / 8;  // 2097152
    size_t t = (size_t)blockIdx.x * 256 + threadIdx.x;
    const float* src;
    _Float16 *hd, *ld;
    bool isW = (t >= NX8);
    if (!isW) {
        src = X + t * 8;
        hd = f16base + XH_OFF + t * 8;
        ld = f16base + XL_OFF + t * 8;
    } else {
        size_t u = t - NX8;
        src = W + u * 8;
        hd = f16base + WH_OFF + u * 8;
        ld = f16base + WL_OFF + u * 8;
    }
    float4 v0 = *(const float4*)src;
    float4 v1 = *(const float4*)(src + 4);
    float v[8] = {v0.x, v0.y, v0.z, v0.w, v1.x, v1.y, v1.z, v1.w};
    f16x8 h, l;
    float s = 0.f;
#pragma unroll
    for (int i = 0; i < 8; ++i) {
        _Float16 hv = (_Float16)v[i];
        h[i] = hv;
        l[i] = (_Float16)(v[i] - (float)hv);
        s += v[i] * v[i];
    }
    __builtin_nontemporal_store(h, (f16x8*)hd);
    __builtin_nontemporal_store(l, (f16x8*)ld);
    if (isW) {  // wave-uniform branch (W region is wave-aligned)
#pragma unroll
        for (int off = 32; off > 0; off >>= 1) s += __shfl_down(s, off, 64);
        if ((threadIdx.x & 63) == 0) ws[WS_WSQ + ((t - NX8) >> 6)] = s;
    }
}

// ---------------------------------------------------------------------------
// Kernel 1 (MFMA): S[m,n] = wsq[n] - 2 * (x_m . w_n) via fp16 3-term split.
// K-loop: round-1 2-phase schedule (measured best: 903 vs 966 1-barrier vs
// 1002 4-phase). Stripe XCD swizzle kept (FETCH halved, counter-verified).
// Epilogue S-stores non-temporal (S read exactly once, much later).
// ---------------------------------------------------------------------------
#define LDSB 24576   // halves per buffer (Ah 8192 | Al 8192 | Bh 4096 | Bl 4096)
#define AH_O 0
#define AL_O 8192
#define BH_O 16384
#define BL_O 20480

__global__ void __launch_bounds__(512, 2) gemm_dist_mfma_kernel(
    const _Float16* __restrict__ f16base, const float* __restrict__ ws,
    float* __restrict__ out) {
    __shared__ __align__(16) _Float16 lds[3 * LDSB];  // 144 KiB

    const int tid = threadIdx.x;
    const int w = tid >> 6;     // wave 0..7
    const int lane = tid & 63;

    // XCD-aware 2D swizzle (bijective): xcd owns an 8-tile bn stripe
    // (W slice 2.1 MB, L2-resident); bm advances every 8 blocks.
    int lin = blockIdx.y * 64 + blockIdx.x;
    int xcd = lin & 7;
    int idx = lin >> 3;
    const int bn = (xcd * 8 + (idx & 7)) * 128;   // 64 bn tiles
    const int bm = (idx >> 3) * 256;              // 128 bm tiles

    const int wr = w >> 1;      // m-quadrant 0..3 (64 rows each)
    const int wc = w & 1;       // n-half     0..1 (64 cols each)
    const int q = lane >> 4;    // frag k-chunk 0..3
    const int fm = lane & 15;   // frag row/col within 16
    const int l4 = lane >> 2;   // stage: row within 16-row group
    const int p = lane & 3;     // stage: chunk position

    f32x4 acc[4][4];
#pragma unroll
    for (int i = 0; i < 4; ++i)
#pragma unroll
        for (int j = 0; j < 4; ++j) acc[i][j] = (f32x4){0.f, 0.f, 0.f, 0.f};

    auto stage = [&](int ks, _Float16* buf, int part) {
        const int kk = ks * 32;
        int g = w * 2 + part;
        int arow = g * 16 + l4;
        int ca = p ^ ((arow >> 1) & 3);
        size_t aoff = (size_t)(bm + arow) * DIM + kk + ca * 8;
        load_lds16(f16base + XH_OFF + aoff, buf + AH_O + g * 512);
        load_lds16(f16base + XL_OFF + aoff, buf + AL_O + g * 512);
        int brow = w * 16 + l4;
        int cb = p ^ ((brow >> 1) & 3);
        size_t boff = (size_t)(bn + brow) * DIM + kk + cb * 8;
        if (part == 0)
            load_lds16(f16base + WH_OFF + boff, buf + BH_O + w * 512);
        else
            load_lds16(f16base + WL_OFF + boff, buf + BL_O + w * 512);
    };

    _Float16* c0 = lds;
    _Float16* c1 = lds + LDSB;
    _Float16* c2 = lds + 2 * LDSB;

    // Prologue: stage ks0 -> c0 (6 loads), ks1 -> c1 (6 loads); wait for c0.
    stage(0, c0, 0); stage(0, c0, 1);
    stage(1, c1, 0); stage(1, c1, 1);
    asm volatile("s_waitcnt vmcnt(6)" ::: "memory");
    __builtin_amdgcn_s_barrier();
    __builtin_amdgcn_sched_barrier(0);

#pragma unroll 1
    for (int ks = 0; ks < 16; ++ks) {
        // ---- phase 1: all B frags + A(i=0,1); stage part 0 of ks+2 ----
        f16x8 bhv[4], blv[4];
#pragma unroll
        for (int j = 0; j < 4; ++j) {
            int bb = wc * 64 + j * 16 + fm;
            int off = bb * 32 + ((q ^ ((bb >> 1) & 3)) * 8);
            bhv[j] = *(const f16x8*)&c0[BH_O + off];
            blv[j] = *(const f16x8*)&c0[BL_O + off];
        }
        f16x8 ah[2], al[2];
#pragma unroll
        for (int i = 0; i < 2; ++i) {
            int am = wr * 64 + i * 16 + fm;
            int off = am * 32 + ((q ^ ((am >> 1) & 3)) * 8);
            ah[i] = *(const f16x8*)&c0[AH_O + off];
            al[i] = *(const f16x8*)&c0[AL_O + off];
        }
        if (ks < 14) stage(ks + 2, c2, 0);
        __builtin_amdgcn_s_setprio(1);
#pragma unroll
        for (int i = 0; i < 2; ++i)
#pragma unroll
            for (int j = 0; j < 4; ++j) {
                acc[i][j] = __builtin_amdgcn_mfma_f32_16x16x32_f16(
                    ah[i], bhv[j], acc[i][j], 0, 0, 0);
                acc[i][j] = __builtin_amdgcn_mfma_f32_16x16x32_f16(
                    ah[i], blv[j], acc[i][j], 0, 0, 0);
                acc[i][j] = __builtin_amdgcn_mfma_f32_16x16x32_f16(
                    al[i], bhv[j], acc[i][j], 0, 0, 0);
            }
        __builtin_amdgcn_s_setprio(0);
        __builtin_amdgcn_s_barrier();

        // ---- phase 2: A(i=2,3), reuse B frags; stage part 1 of ks+2 ----
#pragma unroll
        for (int i = 0; i < 2; ++i) {
            int am = wr * 64 + (i + 2) * 16 + fm;
            int off = am * 32 + ((q ^ ((am >> 1) & 3)) * 8);
            ah[i] = *(const f16x8*)&c0[AH_O + off];
            al[i] = *(const f16x8*)&c0[AL_O + off];
        }
        if (ks < 14) stage(ks + 2, c2, 1);
        __builtin_amdgcn_s_setprio(1);
#pragma unroll
        for (int i = 0; i < 2; ++i)
#pragma unroll
            for (int j = 0; j < 4; ++j) {
                acc[i + 2][j] = __builtin_amdgcn_mfma_f32_16x16x32_f16(
                    ah[i], bhv[j], acc[i + 2][j], 0, 0, 0);
                acc[i + 2][j] = __builtin_amdgcn_mfma_f32_16x16x32_f16(
                    ah[i], blv[j], acc[i + 2][j], 0, 0, 0);
                acc[i + 2][j] = __builtin_amdgcn_mfma_f32_16x16x32_f16(
                    al[i], bhv[j], acc[i + 2][j], 0, 0, 0);
            }
        __builtin_amdgcn_s_setprio(0);
        // Retire buffer (ks+1)'s 6 loads; keep (ks+2)'s 6 in flight.
        if (ks < 14) {
            asm volatile("s_waitcnt vmcnt(6)" ::: "memory");
        } else if (ks == 14) {
            asm volatile("s_waitcnt vmcnt(0)" ::: "memory");
        }
        __builtin_amdgcn_s_barrier();
        __builtin_amdgcn_sched_barrier(0);

        _Float16* t0 = c0; c0 = c1; c1 = c2; c2 = t0;
    }

    // Epilogue: S = wsq[n] - 2*dot (pure NT store).
    // C/D layout: col = lane&15, row = (lane>>4)*4 + r (m89-verified)
    const float* wsq = ws + WS_WSQ;
    float* Dout = out + OUT_P;
    const int q4 = q * 4;
#pragma unroll
    for (int i = 0; i < 4; ++i) {
#pragma unroll
        for (int j = 0; j < 4; ++j) {
            int n = bn + wc * 64 + j * 16 + fm;
            float wn = wsq[n];
#pragma unroll
            for (int r = 0; r < 4; ++r) {
                int m = bm + wr * 64 + i * 16 + q4 + r;
                ntstore1(&Dout[(size_t)m * K_CODES + n],
                         wn - 2.f * acc[i][j][r]);
            }
        }
    }
}

// ---------------------------------------------------------------------------
// Fallback fp32 GEMM (only if ws can't hold f16 buffers): writes S.
// ---------------------------------------------------------------------------
#define BM 128
#define BN 128
#define BK 16

__global__ void __launch_bounds__(256) gemm_dist_fp32_kernel(
    const float* __restrict__ X, const float* __restrict__ W,
    const float* __restrict__ ws, float* __restrict__ out) {
    __shared__ float As[BK][BM];
    __shared__ float Bs[BK][BN];

    const int bn = blockIdx.x * BN;
    const int bm = blockIdx.y * BM;
    const int tid = threadIdx.x;
    const int tx = tid & 15;
    const int ty = tid >> 4;
    const int lr = tid >> 1;
    const int lc = (tid & 1) * 8;

    float acc[8][8];
#pragma unroll
    for (int i = 0; i < 8; ++i)
#pragma unroll
        for (int j = 0; j < 8; ++j) acc[i][j] = 0.f;

    const float* aptr = X + (size_t)(bm + lr) * DIM + lc;
    const float* bptr = W + (size_t)(bn + lr) * DIM + lc;

    for (int k0 = 0; k0 < DIM; k0 += BK) {
        float4 a0 = *(const float4*)(aptr + k0);
        float4 a1 = *(const float4*)(aptr + k0 + 4);
        float4 b0 = *(const float4*)(bptr + k0);
        float4 b1 = *(const float4*)(bptr + k0 + 4);
        __syncthreads();
        As[lc + 0][lr] = a0.x; As[lc + 1][lr] = a0.y;
        As[lc + 2][lr] = a0.z; As[lc + 3][lr] = a0.w;
        As[lc + 4][lr] = a1.x; As[lc + 5][lr] = a1.y;
        As[lc + 6][lr] = a1.z; As[lc + 7][lr] = a1.w;
        Bs[lc + 0][lr] = b0.x; Bs[lc + 1][lr] = b0.y;
        Bs[lc + 2][lr] = b0.z; Bs[lc + 3][lr] = b0.w;
        Bs[lc + 4][lr] = b1.x; Bs[lc + 5][lr] = b1.y;
        Bs[lc + 6][lr] = b1.z; Bs[lc + 7][lr] = b1.w;
        __syncthreads();
#pragma unroll
        for (int kk = 0; kk < BK; ++kk) {
            float a[8], b[8];
            *(float4*)&a[0] = *(const float4*)&As[kk][ty * 8];
            *(float4*)&a[4] = *(const float4*)&As[kk][ty * 8 + 4];
            *(float4*)&b[0] = *(const float4*)&Bs[kk][tx * 8];
            *(float4*)&b[4] = *(const float4*)&Bs[kk][tx * 8 + 4];
#pragma unroll
            for (int i = 0; i < 8; ++i)
#pragma unroll
                for (int j = 0; j < 8; ++j)
                    acc[i][j] = fmaf(a[i], b[j], acc[i][j]);
        }
    }

    const float* wsq = ws + WS_WSQ;
    const int m0 = bm + ty * 8;
    const int n0 = bn + tx * 8;
    float wn[8];
    *(float4*)&wn[0] = *(const float4*)(wsq + n0);
    *(float4*)&wn[4] = *(const float4*)(wsq + n0 + 4);
    float* Dout = out + OUT_P;
#pragma unroll
    for (int i = 0; i < 8; ++i) {
        float4 o0, o1;
        o0.x = wn[0] - 2.f * acc[i][0];
        o0.y = wn[1] - 2.f * acc[i][1];
        o0.z = wn[2] - 2.f * acc[i][2];
        o0.w = wn[3] - 2.f * acc[i][3];
        o1.x = wn[4] - 2.f * acc[i][4];
        o1.y = wn[5] - 2.f * acc[i][5];
        o1.z = wn[6] - 2.f * acc[i][6];
        o1.w = wn[7] - 2.f * acc[i][7];
        float* drow = Dout + (size_t)(m0 + i) * K_CODES + n0;
        *(float4*)(drow) = o0;
        *(float4*)(drow + 4) = o1;
    }
}

// ---------------------------------------------------------------------------
// Kernel 2 (fused): 256 threads, TWO rows per block (rA = b, rB = b+16384),
// software-pipelined: row B's 32 KB of S loads are issued before row A's
// exp/normalize/store phase, so the block always has a full row of loads in
// flight across its reduce barriers. All S/P/Q traffic non-temporal.
// Per-thread row slice: ONE float2 (256 x 2 = 512 floats = one row exactly).
// (Round-5 bug: used [tid] AND [tid+256] -> 2x over-read, OOB on last rows.)
// ---------------------------------------------------------------------------
__global__ void __launch_bounds__(256) probs_quant_kernel(
    const float* __restrict__ X, const float* __restrict__ W,
    float* __restrict__ out, float* __restrict__ ws) {
    const int tid = threadIdx.x;
    const int wv = tid >> 6;
    const int rA = blockIdx.x;
    const int rB = blockIdx.x + N_ROWS / 2;
    __shared__ u64 mred[4];
    __shared__ float sred[4];
    __shared__ float ered[4];

    float* DA = out + OUT_P + (size_t)rA * K_CODES;
    float* DB = out + OUT_P + (size_t)rB * K_CODES;

    // X rows (independent): issue early. One float2/thread = full 512-f row.
    f32x2 xA = ((const f32x2*)(X + (size_t)rA * DIM))[tid];
    f32x2 xB = ((const f32x2*)(X + (size_t)rB * DIM))[tid];

    // ---- row A: load S ----
    f32x4 eA[8];
#pragma unroll
    for (int t = 0; t < 8; ++t) eA[t] = ntload4(DA + (tid + t * 256) * 4);

    // ---- row A: packed (min,argmin) ----
    u64 bestA = ~0ull;
#pragma unroll
    for (int t = 0; t < 8; ++t) {
        unsigned int c0 = (unsigned int)((tid + t * 256) * 4);
#pragma unroll
        for (int c = 0; c < 4; ++c) {
            u64 k = ((u64)fkey(eA[t][c]) << 32) | (c0 + c);
            bestA = k < bestA ? k : bestA;
        }
    }
#pragma unroll
    for (int d = 1; d < 64; d <<= 1) {
        u64 o = __shfl_xor(bestA, d, 64);
        bestA = o < bestA ? o : bestA;
    }
    if ((tid & 63) == 0) mred[wv] = bestA;
    __syncthreads();                                   // sync A1
    u64 bmA = mred[0];
#pragma unroll
    for (int i = 1; i < 4; ++i) bmA = mred[i] < bmA ? mred[i] : bmA;
    const float sminA = fkey_inv((unsigned int)(bmA >> 32));
    const int aminA = (int)(bmA & 0xFFFFFFFFu);

    // ---- issue row B's S loads now (in flight during A's exp/store) ----
    f32x4 eB[8];
#pragma unroll
    for (int t = 0; t < 8; ++t) eB[t] = ntload4(DB + (tid + t * 256) * 4);

    // ---- row A: exp + sum ----
    float sumA = 0.f;
#pragma unroll
    for (int t = 0; t < 8; ++t) {
#pragma unroll
        for (int c = 0; c < 4; ++c) {
            float v = __expf(sminA - eA[t][c]);
            eA[t][c] = v;
            sumA += v;
        }
    }
#pragma unroll
    for (int off = 32; off > 0; off >>= 1) sumA += __shfl_down(sumA, off, 64);
    if ((tid & 63) == 0) sred[wv] = sumA;
    __syncthreads();                                   // sync A2
    const float invA = 1.0f / (sred[0] + sred[1] + sred[2] + sred[3]);

    // ---- row A: normalized NT store ----
#pragma unroll
    for (int t = 0; t < 8; ++t) {
        f32x4 v = eA[t];
        v *= invA;
        ntstore4(DA + (tid + t * 256) * 4, v);
    }

    // ---- row A: quantize + straight-through + err ----
    {
        f32x2 wq = ((const f32x2*)(W + (size_t)aminA * DIM))[tid];
        f32x2 d = wq - xA;
        f32x2 o = xA + d;  // bit-exact straight-through form
        __builtin_nontemporal_store(
            o, (f32x2*)(out + OUT_Q + (size_t)rA * DIM) + tid);
        float err = d.x * d.x + d.y * d.y;
#pragma unroll
        for (int off = 32; off > 0; off >>= 1) err += __shfl_down(err, off, 64);
        if ((tid & 63) == 0) ered[wv] = err;
        __syncthreads();                               // sync A3
        if (tid == 0) {
            ws[WS_ERR + rA] = ered[0] + ered[1] + ered[2] + ered[3];
            atomicAdd(ws + WS_CNT + aminA, 1.0f);
        }
    }

    // ---- row B: packed (min,argmin) (loads have been in flight) ----
    u64 bestB = ~0ull;
#pragma unroll
    for (int t = 0; t < 8; ++t) {
        unsigned int c0 = (unsigned int)((tid + t * 256) * 4);
#pragma unroll
        for (int c = 0; c < 4; ++c) {
            u64 k = ((u64)fkey(eB[t][c]) << 32) | (c0 + c);
            bestB = k < bestB ? k : bestB;
        }
    }
#pragma unroll
    for (int d = 1; d < 64; d <<= 1) {
        u64 o = __shfl_xor(bestB, d, 64);
        bestB = o < bestB ? o : bestB;
    }
    if ((tid & 63) == 0) mred[wv] = bestB;  // safe: mred-A reads ended before A2
    __syncthreads();                                   // sync B1
    u64 bmB = mred[0];
#pragma unroll
    for (int i = 1; i < 4; ++i) bmB = mred[i] < bmB ? mred[i] : bmB;
    const float sminB = fkey_inv((unsigned int)(bmB >> 32));
    const int aminB = (int)(bmB & 0xFFFFFFFFu);

    // ---- row B: exp + sum ----
    float sumB = 0.f;
#pragma unroll
    for (int t = 0; t < 8; ++t) {
#pragma unroll
        for (int c = 0; c < 4; ++c) {
            float v = __expf(sminB - eB[t][c]);
            eB[t][c] = v;
            sumB += v;
        }
    }
#pragma unroll
    for (int off = 32; off > 0; off >>= 1) sumB += __shfl_down(sumB, off, 64);
    if ((tid & 63) == 0) sred[wv] = sumB;   // safe: sred-A reads ended before A3
    __syncthreads();                                   // sync B2
    const float invB = 1.0f / (sred[0] + sred[1] + sred[2] + sred[3]);

    // ---- row B: normalized NT store ----
#pragma unroll
    for (int t = 0; t < 8; ++t) {
        f32x4 v = eB[t];
        v *= invB;
        ntstore4(DB + (tid + t * 256) * 4, v);
    }

    // ---- row B: quantize + straight-through + err ----
    {
        f32x2 wq = ((const f32x2*)(W + (size_t)aminB * DIM))[tid];
        f32x2 d = wq - xB;
        f32x2 o = xB + d;
        __builtin_nontemporal_store(
            o, (f32x2*)(out + OUT_Q + (size_t)rB * DIM) + tid);
        float err = d.x * d.x + d.y * d.y;
#pragma unroll
        for (int off = 32; off > 0; off >>= 1) err += __shfl_down(err, off, 64);
        if ((tid & 63) == 0) ered[wv] = err;  // safe: ered-A read ended before B1
        __syncthreads();                               // sync B3
        if (tid == 0) {
            ws[WS_ERR + rB] = ered[0] + ered[1] + ered[2] + ered[3];
            atomicAdd(ws + WS_CNT + aminB, 1.0f);
        }
    }
}

// ---------------------------------------------------------------------------
// Kernel 3a: 32-block partial reduce of per-row errors + entropy terms.
// ---------------------------------------------------------------------------
__global__ void __launch_bounds__(256) finalize_part_kernel(
    float* __restrict__ ws) {
    __shared__ float red[256];
    const int b = blockIdx.x;   // 0..31
    const int tid = threadIdx.x;

    float errsum = 0.f;
    const int ebase = b * 1024;
#pragma unroll
    for (int j = tid; j < 1024; j += 256) errsum += ws[WS_ERR + ebase + j];

    float p = ws[WS_CNT + b * 256 + tid] * (1.0f / (float)N_ROWS);
    float ent = -p * logf(p + 1e-10f);

    red[tid] = errsum;
    __syncthreads();
    for (int st = 128; st > 0; st >>= 1) {
        if (tid < st) red[tid] += red[tid + st];
        __syncthreads();
    }
    if (tid == 0) ws[WS_RED + b] = red[0];
    __syncthreads();
    red[tid] = ent;
    __syncthreads();
    for (int st = 128; st > 0; st >>= 1) {
        if (tid < st) red[tid] += red[tid + st];
        __syncthreads();
    }
    if (tid == 0) ws[WS_RED + 32 + b] = red[0];
}

// ---------------------------------------------------------------------------
// Kernel 3b: final combine (one wave).
// ---------------------------------------------------------------------------
__global__ void __launch_bounds__(64) finalize_fin_kernel(
    float* __restrict__ out, const float* __restrict__ ws) {
    const int tid = threadIdx.x;
    float ev = tid < 32 ? ws[WS_RED + tid] : 0.f;
    float nv = tid < 32 ? ws[WS_RED + 32 + tid] : 0.f;
#pragma unroll
    for (int off = 32; off > 0; off >>= 1) {
        ev += __shfl_down(ev, off, 64);
        nv += __shfl_down(nv, off, 64);
    }
    if (tid == 0) {
        float mse = ev * (1.0f / ((float)N_ROWS * (float)DIM));
        out[OUT_LOSS] = mse + 0.25f * mse;
        out[OUT_PERP] = expf(nv);
    }
}

// ---------------------------------------------------------------------------
extern "C" void kernel_launch(void* const* d_in, const int* in_sizes, int n_in,
                              void* d_out, int out_size, void* d_ws, size_t ws_size,
                              hipStream_t stream) {
    const float* X = (const float*)d_in[0];  // [32768, 512]
    const float* W = (const float*)d_in[1];  // [8192, 512]
    float* out = (float*)d_out;
    float* ws = (float*)d_ws;

    // zero the histogram (ws is poisoned 0xAA); WS_ERR/WS_RED fully overwritten
    hipMemsetAsync(ws + WS_CNT, 0, K_CODES * sizeof(float), stream);

    if (ws_size >= WS_NEEDED) {
        _Float16* f16base = (_Float16*)(ws + WS_F16);
        const int conv_blocks =
            (int)(((size_t)(N_ROWS + K_CODES) * DIM / 8 + 255) / 256);
        // convert also computes wsq (fused W row-norms)
        convert_split_kernel<<<conv_blocks, 256, 0, stream>>>(X, W, f16base, ws);

        dim3 ggrid(64, 128);  // bn-tiles x bm-tiles
        gemm_dist_mfma_kernel<<<ggrid, 512, 0, stream>>>(f16base, ws, out);
    } else {
        wsq_kernel<<<K_CODES, 64, 0, stream>>>(W, ws);
        dim3 ggrid(K_CODES / BN, N_ROWS / BM);
        gemm_dist_fp32_kernel<<<ggrid, 256, 0, stream>>>(X, W, ws, out);
    }

    probs_quant_kernel<<<N_ROWS / 2, 256, 0, stream>>>(X, W, out, ws);
    finalize_part_kernel<<<32, 256, 0, stream>>>(ws);
    finalize_fin_kernel<<<1, 64, 0, stream>>>(out, ws);
}